// Round 1
// baseline (330.559 us; speedup 1.0000x reference)
//
#include <hip/hip_runtime.h>
#include <math.h>

typedef _Float16 hv8 __attribute__((ext_vector_type(8)));
typedef _Float16 hv4 __attribute__((ext_vector_type(4)));
typedef float f32x4 __attribute__((ext_vector_type(4)));

#define LDS_AS(p) ((__attribute__((address_space(3))) void*)(p))
#define GLB_AS(p) ((const __attribute__((address_space(1))) void*)(p))

// ---------------- fp32 -> fp16 convert ----------------
__global__ void cvt_kernel(const float* __restrict__ in, _Float16* __restrict__ out, int n) {
  int i = (blockIdx.x * blockDim.x + threadIdx.x) * 4;
  const int stride = gridDim.x * blockDim.x * 4;
  for (; i < n; i += stride) {
    const float4 v = *reinterpret_cast<const float4*>(in + i);
    hv4 o = {(_Float16)v.x, (_Float16)v.y, (_Float16)v.z, (_Float16)v.w};
    *reinterpret_cast<hv4*>(out + i) = o;
  }
}

// ---------------- RoPE in-place on fp16 [4096][1024], heads of 64 ----------------
__global__ void rope_kernel(_Float16* __restrict__ T) {
  const int idx = blockIdx.x * blockDim.x + threadIdx.x;  // 0 .. 2097151
  const int pair = idx & 511;  // h*32 + i
  const int row = idx >> 9;    // 0..4095  (b*2048 + pos)
  const int pos = row & 2047;
  const int h = pair >> 5, i = pair & 31;
  const float p = (float)(2 * i) * (1.0f / 64.0f);
  const float freq = powf(10000.0f, -p);
  const float ang = (float)pos * freq;
  float s, c;
  sincosf(ang, &s, &c);
  const size_t off = (size_t)row * 1024 + h * 64 + 2 * i;
  const float e = (float)T[off];
  const float o = (float)T[off + 1];
  T[off]     = (_Float16)(e * c - o * s);
  T[off + 1] = (_Float16)(e * s + o * c);
}

// ---------------- NT GEMM: C[m][n] = sum_k A[m][k] * B[n][k] ----------------
// A: M x K fp16 row-major, B: N x K fp16 row-major. 128x128 tile, BK=32,
// 4 waves, each wave 64x64 (4x4 frags of 16x16x32 MFMA).
template <typename OutT>
__global__ __launch_bounds__(256) void gemm_nt(const _Float16* __restrict__ A,
                                               const _Float16* __restrict__ B,
                                               OutT* __restrict__ C,
                                               const int M, const int N, const int K) {
  __shared__ __align__(16) _Float16 As[128 * 32];
  __shared__ __align__(16) _Float16 Bs[128 * 32];
  const int t = threadIdx.x;
  const int w = t >> 6, lane = t & 63;
  const int wr = w >> 1, wc = w & 1;
  const int g = lane >> 4, lr = lane & 15;
  const int mBase = blockIdx.y * 128, nBase = blockIdx.x * 128;

  f32x4 acc[4][4];
#pragma unroll
  for (int a = 0; a < 4; a++)
#pragma unroll
    for (int b = 0; b < 4; b++) acc[a][b] = {0.f, 0.f, 0.f, 0.f};

  const int srow = t >> 2;        // 0..63
  const int scol = (t & 3) * 8;   // 0,8,16,24
  for (int k0 = 0; k0 < K; k0 += 32) {
#pragma unroll
    for (int i = 0; i < 2; i++) {
      const _Float16* ga = A + (size_t)(mBase + i * 64 + srow) * K + k0 + scol;
      __builtin_amdgcn_global_load_lds(GLB_AS(ga), LDS_AS(As + (i * 256 + w * 64) * 8), 16, 0, 0);
      const _Float16* gb = B + (size_t)(nBase + i * 64 + srow) * K + k0 + scol;
      __builtin_amdgcn_global_load_lds(GLB_AS(gb), LDS_AS(Bs + (i * 256 + w * 64) * 8), 16, 0, 0);
    }
    __syncthreads();
    hv8 af[4], bfr[4];
#pragma unroll
    for (int mi = 0; mi < 4; mi++)
      af[mi] = *reinterpret_cast<const hv8*>(As + (wr * 64 + mi * 16 + lr) * 32 + g * 8);
#pragma unroll
    for (int ni = 0; ni < 4; ni++)
      bfr[ni] = *reinterpret_cast<const hv8*>(Bs + (wc * 64 + ni * 16 + lr) * 32 + g * 8);
#pragma unroll
    for (int mi = 0; mi < 4; mi++)
#pragma unroll
      for (int ni = 0; ni < 4; ni++)
        acc[mi][ni] = __builtin_amdgcn_mfma_f32_16x16x32_f16(af[mi], bfr[ni], acc[mi][ni], 0, 0, 0);
    __syncthreads();
  }
  // epilogue: C/D layout col=lane&15, row=(lane>>4)*4+j  [verified m89/m91]
#pragma unroll
  for (int mi = 0; mi < 4; mi++) {
#pragma unroll
    for (int j = 0; j < 4; j++) {
      const size_t row = mBase + wr * 64 + mi * 16 + g * 4 + j;
#pragma unroll
      for (int ni = 0; ni < 4; ni++) {
        const int col = nBase + wc * 64 + ni * 16 + lr;
        C[row * N + col] = (OutT)acc[mi][ni][j];
      }
    }
  }
}

// ---------------- flash causal attention ----------------
// 1 wave per block; block = 16 q-rows of one (b,h). KV tiles of 32.
// Q,K,V,O layout: [b][n][h*64+d] fp16 (stride 1024).
__global__ __launch_bounds__(64) void attn_kernel(const _Float16* __restrict__ Q,
                                                  const _Float16* __restrict__ K,
                                                  const _Float16* __restrict__ V,
                                                  _Float16* __restrict__ O) {
  __shared__ __align__(16) _Float16 Vs[32 * 64];
  __shared__ __align__(16) _Float16 Ps[16 * 32];
  const int lane = threadIdx.x;
  const int g = lane >> 4, lr = lane & 15;
  const int m0 = blockIdx.x * 16;
  const int b = blockIdx.y >> 4, h = blockIdx.y & 15;
  const size_t base = ((size_t)b * 2048) * 1024 + (size_t)h * 64;
  const _Float16* Qp = Q + base;
  const _Float16* Kp = K + base;
  const _Float16* Vp = V + base;
  _Float16* Op = O + base;

  // Q fragments held in registers for the whole KV loop (A-frag: m=lr, k=g*8+i)
  hv8 qf[2];
#pragma unroll
  for (int ks = 0; ks < 2; ks++)
    qf[ks] = *reinterpret_cast<const hv8*>(Qp + (size_t)(m0 + lr) * 1024 + ks * 32 + g * 8);

  f32x4 oacc[4];
#pragma unroll
  for (int d = 0; d < 4; d++) oacc[d] = {0.f, 0.f, 0.f, 0.f};
  float mrow[4], lrow[4];
#pragma unroll
  for (int j = 0; j < 4; j++) { mrow[j] = -INFINITY; lrow[j] = 0.f; }

  const int qmax = m0 + 15;
  for (int kv0 = 0; kv0 <= qmax; kv0 += 32) {
    // stage V tile [32][64] row-major into LDS (vector copies, coalesced)
#pragma unroll
    for (int it = 0; it < 4; it++) {
      const int e = it * 64 + lane;
      const int r = e >> 3, c0 = (e & 7) * 8;
      *reinterpret_cast<hv8*>(Vs + r * 64 + c0) =
          *reinterpret_cast<const hv8*>(Vp + (size_t)(kv0 + r) * 1024 + c0);
    }
    // S = Q K^T : B-frag straight from global (L2-resident K)
    f32x4 s0 = {0.f, 0.f, 0.f, 0.f}, s1 = {0.f, 0.f, 0.f, 0.f};
#pragma unroll
    for (int ks = 0; ks < 2; ks++) {
      const hv8 kf0 = *reinterpret_cast<const hv8*>(Kp + (size_t)(kv0 + lr) * 1024 + ks * 32 + g * 8);
      const hv8 kf1 = *reinterpret_cast<const hv8*>(Kp + (size_t)(kv0 + 16 + lr) * 1024 + ks * 32 + g * 8);
      s0 = __builtin_amdgcn_mfma_f32_16x16x32_f16(qf[ks], kf0, s0, 0, 0, 0);
      s1 = __builtin_amdgcn_mfma_f32_16x16x32_f16(qf[ks], kf1, s1, 0, 0, 0);
    }
    // online softmax (rows live in 16-lane groups; wave-parallel shfl reduce)
#pragma unroll
    for (int j = 0; j < 4; j++) {
      const int q = m0 + g * 4 + j;
      float v0 = (kv0 + lr > q) ? -INFINITY : s0[j] * 0.125f;
      float v1 = (kv0 + 16 + lr > q) ? -INFINITY : s1[j] * 0.125f;
      float rm = fmaxf(v0, v1);
#pragma unroll
      for (int off = 1; off < 16; off <<= 1) rm = fmaxf(rm, __shfl_xor(rm, off));
      const float mn = fmaxf(mrow[j], rm);
      const float corr = __expf(mrow[j] - mn);  // first iter: exp(-inf)=0
      const float p0 = __expf(v0 - mn);
      const float p1 = __expf(v1 - mn);
      float rs = p0 + p1;
#pragma unroll
      for (int off = 1; off < 16; off <<= 1) rs += __shfl_xor(rs, off);
      lrow[j] = lrow[j] * corr + rs;
      mrow[j] = mn;
#pragma unroll
      for (int d = 0; d < 4; d++) oacc[d][j] *= corr;
      Ps[(g * 4 + j) * 32 + lr] = (_Float16)p0;
      Ps[(g * 4 + j) * 32 + 16 + lr] = (_Float16)p1;
    }
    __syncthreads();
    // O += P V   (A-frag = P from LDS; B-frag = V column slices, scalar reads)
    const hv8 pa = *reinterpret_cast<const hv8*>(Ps + lr * 32 + g * 8);
#pragma unroll
    for (int d = 0; d < 4; d++) {
      hv8 vb;
#pragma unroll
      for (int i = 0; i < 8; i++) vb[i] = Vs[(g * 8 + i) * 64 + d * 16 + lr];
      oacc[d] = __builtin_amdgcn_mfma_f32_16x16x32_f16(pa, vb, oacc[d], 0, 0, 0);
    }
    __syncthreads();
  }
#pragma unroll
  for (int j = 0; j < 4; j++) {
    const float inv = 1.0f / lrow[j];
    const size_t row = m0 + g * 4 + j;
#pragma unroll
    for (int d = 0; d < 4; d++)
      Op[row * 1024 + d * 16 + lr] = (_Float16)(oacc[d][j] * inv);
  }
}

extern "C" void kernel_launch(void* const* d_in, const int* in_sizes, int n_in,
                              void* d_out, int out_size, void* d_ws, size_t ws_size,
                              hipStream_t stream) {
  const float* x = (const float*)d_in[0];
  const float* wq = (const float*)d_in[1];
  const float* wk = (const float*)d_in[2];
  const float* wv = (const float*)d_in[3];
  const float* wo = (const float*)d_in[4];
  float* out = (float*)d_out;
  char* ws = (char*)d_ws;
  const size_t MB = 1ull << 20;
  _Float16* xb  = (_Float16*)(ws + 0 * MB);   // 8 MB
  _Float16* wqb = (_Float16*)(ws + 8 * MB);   // 2 MB
  _Float16* wkb = (_Float16*)(ws + 10 * MB);  // 2 MB
  _Float16* wvb = (_Float16*)(ws + 12 * MB);  // 2 MB
  _Float16* wob = (_Float16*)(ws + 14 * MB);  // 2 MB
  _Float16* Qb  = (_Float16*)(ws + 16 * MB);  // 8 MB
  _Float16* Kb  = (_Float16*)(ws + 24 * MB);  // 8 MB
  _Float16* Vb  = (_Float16*)(ws + 32 * MB);  // 8 MB
  _Float16* Ab  = (_Float16*)(ws + 40 * MB);  // 8 MB  (total 48 MB)

  cvt_kernel<<<2048, 256, 0, stream>>>(x, xb, 4194304);
  cvt_kernel<<<512, 256, 0, stream>>>(wq, wqb, 1048576);
  cvt_kernel<<<512, 256, 0, stream>>>(wk, wkb, 1048576);
  cvt_kernel<<<512, 256, 0, stream>>>(wv, wvb, 1048576);
  cvt_kernel<<<512, 256, 0, stream>>>(wo, wob, 1048576);

  dim3 gg(8, 32);  // N/128, M/128
  gemm_nt<_Float16><<<gg, 256, 0, stream>>>(xb, wqb, Qb, 4096, 1024, 1024);
  gemm_nt<_Float16><<<gg, 256, 0, stream>>>(xb, wkb, Kb, 4096, 1024, 1024);
  gemm_nt<_Float16><<<gg, 256, 0, stream>>>(xb, wvb, Vb, 4096, 1024, 1024);

  rope_kernel<<<8192, 256, 0, stream>>>(Qb);
  rope_kernel<<<8192, 256, 0, stream>>>(Kb);

  dim3 ga(128, 32);  // N/16 q-tiles, B*H
  attn_kernel<<<ga, 64, 0, stream>>>(Qb, Kb, Vb, Ab);

  gemm_nt<float><<<gg, 256, 0, stream>>>(Ab, wob, out, 4096, 1024, 1024);
}

// Round 3
// 209.709 us; speedup vs baseline: 1.5763x; 1.5763x over previous
//
#include <hip/hip_runtime.h>
#include <math.h>

typedef _Float16 hv8 __attribute__((ext_vector_type(8)));
typedef _Float16 hv4 __attribute__((ext_vector_type(4)));
typedef _Float16 hv2 __attribute__((ext_vector_type(2)));
typedef float f32x4 __attribute__((ext_vector_type(4)));

#define LDS_AS(p) ((__attribute__((address_space(3))) void*)(p))
#define GLB_AS(p) ((const __attribute__((address_space(1))) void*)(p))

// ---------------- fp32 -> fp16 convert ----------------
__global__ void cvt_kernel(const float* __restrict__ in, _Float16* __restrict__ out, int n) {
  int i = (blockIdx.x * blockDim.x + threadIdx.x) * 4;
  const int stride = gridDim.x * blockDim.x * 4;
  for (; i < n; i += stride) {
    const float4 v = *reinterpret_cast<const float4*>(in + i);
    hv4 o = {(_Float16)v.x, (_Float16)v.y, (_Float16)v.z, (_Float16)v.w};
    *reinterpret_cast<hv4*>(out + i) = o;
  }
}

// ---------------- RoPE in-place on fused QKV [4096][3072]; Q|K = cols 0..2047 ----------------
__global__ void rope_kernel(_Float16* __restrict__ T) {
  const int idx = blockIdx.x * blockDim.x + threadIdx.x;  // 4096 rows * 1024 pairs
  const int pair = idx & 1023;  // hh*32 + i  (hh 0..31 spans Q heads 0-15, K heads 0-15)
  const int row = idx >> 10;    // b*2048 + pos
  const int pos = row & 2047;
  const int hh = pair >> 5, i = pair & 31;
  // freq = 10000^(-2i/64) = 2^(-i * log2(10000)/32)
  const float freq = exp2f((float)i * (-13.287712379549449f / 32.0f));
  const float ang = (float)pos * freq;
  float s, c;
  sincosf(ang, &s, &c);
  const size_t off = (size_t)row * 3072 + hh * 64 + 2 * i;
  hv2 v = *reinterpret_cast<const hv2*>(T + off);
  const float e = (float)v[0];
  const float o = (float)v[1];
  v[0] = (_Float16)(e * c - o * s);
  v[1] = (_Float16)(e * s + o * c);
  *reinterpret_cast<hv2*>(T + off) = v;
}

// ---------------- V transpose: QKV cols 2048+ -> Vt[(b*16+h)*64 + d][2048] ----------------
__global__ __launch_bounds__(256) void vtrans_kernel(const _Float16* __restrict__ QKV,
                                                     _Float16* __restrict__ Vt) {
  __shared__ __align__(16) _Float16 Ts[64][72];
  const int t = threadIdx.x;
  const int n0 = blockIdx.x * 64;
  const int bh = blockIdx.y;
  const int b = bh >> 4, h = bh & 15;
  const _Float16* src = QKV + (size_t)(b * 2048 + n0) * 3072 + 2048 + h * 64;
#pragma unroll
  for (int i = 0; i < 2; i++) {
    const int s = i * 256 + t, r = s >> 3, c = (s & 7) * 8;
    *reinterpret_cast<hv8*>(&Ts[r][c]) = *reinterpret_cast<const hv8*>(src + (size_t)r * 3072 + c);
  }
  __syncthreads();
  _Float16* dst = Vt + (size_t)bh * 64 * 2048 + n0;
#pragma unroll
  for (int i = 0; i < 2; i++) {
    const int s = i * 256 + t, c = s >> 3, r0 = (s & 7) * 8;
    hv8 o;
#pragma unroll
    for (int k = 0; k < 8; k++) o[k] = Ts[r0 + k][c];
    *reinterpret_cast<hv8*>(dst + (size_t)c * 2048 + r0) = o;
  }
}

// ---------------- NT GEMM: C[m][n] = sum_k A[m][k] * B[n][k] ----------------
// BM x 128 tile, BK=32, 4 waves (2x2), each wave (BM/2) x 64.
template <int BM, typename OutT>
__global__ __launch_bounds__(256) void gemm_nt(const _Float16* __restrict__ A,
                                               const _Float16* __restrict__ B,
                                               OutT* __restrict__ C,
                                               const int M, const int N, const int K) {
  constexpr int MI = BM / 32;      // m-frags per wave
  constexpr int ALOADS = BM / 64;  // global_load_lds issues per thread for A
  __shared__ __align__(16) _Float16 As[BM * 32];
  __shared__ __align__(16) _Float16 Bs[128 * 32];
  const int t = threadIdx.x;
  const int w = t >> 6, lane = t & 63;
  const int wr = w >> 1, wc = w & 1;
  const int g = lane >> 4, lr = lane & 15;
  const int mBase = blockIdx.y * BM, nBase = blockIdx.x * 128;

  f32x4 acc[MI][4];
#pragma unroll
  for (int a = 0; a < MI; a++)
#pragma unroll
    for (int bb = 0; bb < 4; bb++) acc[a][bb] = {0.f, 0.f, 0.f, 0.f};

  const int srow = t >> 2;        // 0..63
  const int scol = (t & 3) * 8;   // 0,8,16,24
  for (int k0 = 0; k0 < K; k0 += 32) {
#pragma unroll
    for (int i = 0; i < ALOADS; i++) {
      const _Float16* ga = A + (size_t)(mBase + i * 64 + srow) * K + k0 + scol;
      __builtin_amdgcn_global_load_lds(GLB_AS(ga), LDS_AS(As + (i * 256 + w * 64) * 8), 16, 0, 0);
    }
#pragma unroll
    for (int i = 0; i < 2; i++) {
      const _Float16* gb = B + (size_t)(nBase + i * 64 + srow) * K + k0 + scol;
      __builtin_amdgcn_global_load_lds(GLB_AS(gb), LDS_AS(Bs + (i * 256 + w * 64) * 8), 16, 0, 0);
    }
    __syncthreads();
    hv8 af[MI], bfr[4];
#pragma unroll
    for (int mi = 0; mi < MI; mi++)
      af[mi] = *reinterpret_cast<const hv8*>(As + (wr * (BM / 2) + mi * 16 + lr) * 32 + g * 8);
#pragma unroll
    for (int ni = 0; ni < 4; ni++)
      bfr[ni] = *reinterpret_cast<const hv8*>(Bs + (wc * 64 + ni * 16 + lr) * 32 + g * 8);
#pragma unroll
    for (int mi = 0; mi < MI; mi++)
#pragma unroll
      for (int ni = 0; ni < 4; ni++)
        acc[mi][ni] = __builtin_amdgcn_mfma_f32_16x16x32_f16(af[mi], bfr[ni], acc[mi][ni], 0, 0, 0);
    __syncthreads();
  }
  // epilogue: C/D layout col=lane&15, row=(lane>>4)*4+j
#pragma unroll
  for (int mi = 0; mi < MI; mi++) {
#pragma unroll
    for (int j = 0; j < 4; j++) {
      const size_t row = mBase + wr * (BM / 2) + mi * 16 + g * 4 + j;
#pragma unroll
      for (int ni = 0; ni < 4; ni++) {
        const int col = nBase + wc * 64 + ni * 16 + lr;
        C[row * N + col] = (OutT)acc[mi][ni][j];
      }
    }
  }
}

// ---------------- flash causal attention ----------------
// 4 waves/block; block = 64 q-rows of one (b,h); wave w owns rows m0+w*16..+15.
// KV tiles of 64. K from QKV (stride 3072, col 1024+h*64); V pre-transposed Vt[d][n].
// K/V tiles staged via global_load_lds with XOR-swizzled source (chunk ^= row&7)
// so fragment ds_read_b128 are conflict-light.
__global__ __launch_bounds__(256) void attn_kernel(const _Float16* __restrict__ QKV,
                                                   const _Float16* __restrict__ Vt,
                                                   _Float16* __restrict__ O) {
  __shared__ __align__(16) _Float16 Ks[64 * 64];
  __shared__ __align__(16) _Float16 Vs[64 * 64];
  __shared__ __align__(16) _Float16 Ps[4][16 * 72];
  const int t = threadIdx.x;
  const int w = t >> 6, lane = t & 63;
  const int g = lane >> 4, lr = lane & 15;
  const int m0 = blockIdx.x * 64;
  const int bh = blockIdx.y;
  const int b = bh >> 4, h = bh & 15;
  const _Float16* Qp = QKV + (size_t)b * 2048 * 3072 + h * 64;
  const _Float16* Kp = Qp + 1024;
  const _Float16* Vp = Vt + (size_t)bh * 64 * 2048;
  _Float16* Op = O + (size_t)b * 2048 * 1024 + h * 64;

  // Q fragments in registers for the whole KV loop (A-frag: m=lr, k=g*8+i)
  hv8 qf[2];
#pragma unroll
  for (int ks = 0; ks < 2; ks++)
    qf[ks] = *reinterpret_cast<const hv8*>(Qp + (size_t)(m0 + w * 16 + lr) * 3072 + ks * 32 + g * 8);

  f32x4 oacc[4];
#pragma unroll
  for (int d = 0; d < 4; d++) oacc[d] = {0.f, 0.f, 0.f, 0.f};
  float mrow[4], lrow[4];
#pragma unroll
  for (int j = 0; j < 4; j++) { mrow[j] = -INFINITY; lrow[j] = 0.f; }

  for (int kv0 = 0; kv0 <= m0; kv0 += 64) {
    // stage K tile [64 kv][64 d] and V tile [64 d][64 kv], swizzled source
#pragma unroll
    for (int i = 0; i < 2; i++) {
      const int s = i * 256 + t;
      const int r = s >> 3;
      const int cs = ((s & 7) ^ (r & 7)) * 8;
      __builtin_amdgcn_global_load_lds(GLB_AS(Kp + (size_t)(kv0 + r) * 3072 + cs),
                                       LDS_AS(Ks + (i * 256 + w * 64) * 8), 16, 0, 0);
      __builtin_amdgcn_global_load_lds(GLB_AS(Vp + (size_t)r * 2048 + kv0 + cs),
                                       LDS_AS(Vs + (i * 256 + w * 64) * 8), 16, 0, 0);
    }
    __syncthreads();

    // S = Q K^T  (4 n-frags x 2 k-steps)
    f32x4 sf[4];
#pragma unroll
    for (int nf = 0; nf < 4; nf++) sf[nf] = {0.f, 0.f, 0.f, 0.f};
#pragma unroll
    for (int ks = 0; ks < 2; ks++)
#pragma unroll
      for (int nf = 0; nf < 4; nf++) {
        const hv8 kf = *reinterpret_cast<const hv8*>(
            Ks + (nf * 16 + lr) * 64 + (((ks * 4 + g) ^ (lr & 7)) * 8));
        sf[nf] = __builtin_amdgcn_mfma_f32_16x16x32_f16(qf[ks], kf, sf[nf], 0, 0, 0);
      }

    // online softmax; only the diagonal tile needs masking
    const bool diag = (kv0 == m0);
#pragma unroll
    for (int j = 0; j < 4; j++) {
      const int qloc = w * 16 + g * 4 + j;
      float v[4];
#pragma unroll
      for (int nf = 0; nf < 4; nf++) {
        v[nf] = sf[nf][j] * 0.125f;
        if (diag && (nf * 16 + lr > qloc)) v[nf] = -INFINITY;
      }
      float rm = fmaxf(fmaxf(v[0], v[1]), fmaxf(v[2], v[3]));
#pragma unroll
      for (int off = 1; off < 16; off <<= 1) rm = fmaxf(rm, __shfl_xor(rm, off));
      const float mn = fmaxf(mrow[j], rm);
      const float corr = __expf(mrow[j] - mn);  // first tile: exp(-inf)=0
      float p[4];
      float rs = 0.f;
#pragma unroll
      for (int nf = 0; nf < 4; nf++) { p[nf] = __expf(v[nf] - mn); rs += p[nf]; }
#pragma unroll
      for (int off = 1; off < 16; off <<= 1) rs += __shfl_xor(rs, off);
      lrow[j] = lrow[j] * corr + rs;
      mrow[j] = mn;
#pragma unroll
      for (int d = 0; d < 4; d++) oacc[d][j] *= corr;
#pragma unroll
      for (int nf = 0; nf < 4; nf++)
        Ps[w][(g * 4 + j) * 72 + nf * 16 + lr] = (_Float16)p[nf];
    }
    __syncthreads();  // cross-lane P visibility within wave region

    // O += P V  (A-frag = P rows; B-frag = Vt rows, both vector reads)
    hv8 pa[2];
#pragma unroll
    for (int ks = 0; ks < 2; ks++)
      pa[ks] = *reinterpret_cast<const hv8*>(&Ps[w][lr * 72 + ks * 32 + g * 8]);
#pragma unroll
    for (int dblk = 0; dblk < 4; dblk++)
#pragma unroll
      for (int ks = 0; ks < 2; ks++) {
        const hv8 vb = *reinterpret_cast<const hv8*>(
            Vs + (dblk * 16 + lr) * 64 + (((ks * 4 + g) ^ (lr & 7)) * 8));
        oacc[dblk] = __builtin_amdgcn_mfma_f32_16x16x32_f16(pa[ks], vb, oacc[dblk], 0, 0, 0);
      }
    __syncthreads();  // protect Ks/Vs for next tile's staging
  }

#pragma unroll
  for (int j = 0; j < 4; j++) {
    const float inv = 1.0f / lrow[j];
    const size_t row = m0 + w * 16 + g * 4 + j;
#pragma unroll
    for (int dblk = 0; dblk < 4; dblk++)
      Op[row * 1024 + dblk * 16 + lr] = (_Float16)(oacc[dblk][j] * inv);
  }
}

extern "C" void kernel_launch(void* const* d_in, const int* in_sizes, int n_in,
                              void* d_out, int out_size, void* d_ws, size_t ws_size,
                              hipStream_t stream) {
  const float* x = (const float*)d_in[0];
  const float* wq = (const float*)d_in[1];
  const float* wk = (const float*)d_in[2];
  const float* wv = (const float*)d_in[3];
  const float* wo = (const float*)d_in[4];
  float* out = (float*)d_out;
  char* ws = (char*)d_ws;
  const size_t MB = 1ull << 20;
  _Float16* xb   = (_Float16*)(ws + 0 * MB);   // 8 MB (A operand for QKV gemm)
  _Float16* wqkv = (_Float16*)(ws + 8 * MB);   // 6 MB (wq|wk|wv contiguous rows)
  _Float16* wob  = (_Float16*)(ws + 14 * MB);  // 2 MB
  _Float16* QKV  = (_Float16*)(ws + 16 * MB);  // 24 MB [4096][3072]
  _Float16* Vtb  = (_Float16*)(ws + 40 * MB);  // 8 MB  [32*64][2048]
  _Float16* Ab   = (_Float16*)(ws + 0 * MB);   // 8 MB  (reuses xb after QKV gemm)

  cvt_kernel<<<2048, 256, 0, stream>>>(x, xb, 4194304);
  cvt_kernel<<<512, 256, 0, stream>>>(wq, wqkv, 1048576);
  cvt_kernel<<<512, 256, 0, stream>>>(wk, wqkv + 1048576, 1048576);
  cvt_kernel<<<512, 256, 0, stream>>>(wv, wqkv + 2097152, 1048576);
  cvt_kernel<<<512, 256, 0, stream>>>(wo, wob, 1048576);

  // fused Q|K|V projection: [4096][3072]
  gemm_nt<128, _Float16><<<dim3(24, 32), 256, 0, stream>>>(xb, wqkv, QKV, 4096, 3072, 1024);

  rope_kernel<<<16384, 256, 0, stream>>>(QKV);
  vtrans_kernel<<<dim3(32, 32), 256, 0, stream>>>(QKV, Vtb);

  attn_kernel<<<dim3(32, 32), 256, 0, stream>>>(QKV, Vtb, Ab);

  gemm_nt<64, float><<<dim3(8, 64), 256, 0, stream>>>(Ab, wob, out, 4096, 1024, 1024);
}

// Round 4
// 166.678 us; speedup vs baseline: 1.9832x; 1.2582x over previous
//
#include <hip/hip_runtime.h>
#include <math.h>

typedef _Float16 hv8 __attribute__((ext_vector_type(8)));
typedef _Float16 hv4 __attribute__((ext_vector_type(4)));
typedef _Float16 hv2 __attribute__((ext_vector_type(2)));
typedef float f32x4 __attribute__((ext_vector_type(4)));

#define LDS_AS(p) ((__attribute__((address_space(3))) void*)(p))
#define GLB_AS(p) ((const __attribute__((address_space(1))) void*)(p))

// ---------------- fp32 -> fp16 convert (x) ----------------
__global__ void cvt_kernel(const float* __restrict__ in, _Float16* __restrict__ out, int n) {
  int i = (blockIdx.x * blockDim.x + threadIdx.x) * 4;
  const int stride = gridDim.x * blockDim.x * 4;
  for (; i < n; i += stride) {
    const float4 v = *reinterpret_cast<const float4*>(in + i);
    hv4 o = {(_Float16)v.x, (_Float16)v.y, (_Float16)v.z, (_Float16)v.w};
    *reinterpret_cast<hv4*>(out + i) = o;
  }
}

// ---------------- fp32 -> fp16 convert, all 4 weights in one launch ----------------
__global__ void cvt_w_kernel(const float* __restrict__ wq, const float* __restrict__ wk,
                             const float* __restrict__ wv, const float* __restrict__ wo,
                             _Float16* __restrict__ wqkv, _Float16* __restrict__ wob) {
  const int i = (blockIdx.x * blockDim.x + threadIdx.x) * 4;  // 0 .. 4M-4
  const int seg = i >> 20;           // uniform per block (1M-elem segments)
  const int r = i & 1048575;
  const float* s = (seg == 0) ? wq : (seg == 1) ? wk : (seg == 2) ? wv : wo;
  _Float16* d = (seg < 3) ? (wqkv + (size_t)seg * 1048576) : wob;
  const float4 v = *reinterpret_cast<const float4*>(s + r);
  hv4 o = {(_Float16)v.x, (_Float16)v.y, (_Float16)v.z, (_Float16)v.w};
  *reinterpret_cast<hv4*>(d + r) = o;
}

// ---------------- RoPE in-place on fused QKV [4096][3072]; Q|K = cols 0..2047 ----------------
__global__ void rope_kernel(_Float16* __restrict__ T) {
  const int idx = blockIdx.x * blockDim.x + threadIdx.x;  // 4096 rows * 1024 pairs
  const int pair = idx & 1023;  // hh*32 + i
  const int row = idx >> 10;    // b*2048 + pos
  const int pos = row & 2047;
  const int hh = pair >> 5, i = pair & 31;
  const float freq = exp2f((float)i * (-13.287712379549449f / 32.0f));
  const float ang = (float)pos * freq;
  float s, c;
  sincosf(ang, &s, &c);
  const size_t off = (size_t)row * 3072 + hh * 64 + 2 * i;
  hv2 v = *reinterpret_cast<const hv2*>(T + off);
  const float e = (float)v[0];
  const float o = (float)v[1];
  v[0] = (_Float16)(e * c - o * s);
  v[1] = (_Float16)(e * s + o * c);
  *reinterpret_cast<hv2*>(T + off) = v;
}

// ---------------- V transpose: QKV cols 2048+ -> Vt[(b*16+h)*64 + d][2048] ----------------
__global__ __launch_bounds__(256) void vtrans_kernel(const _Float16* __restrict__ QKV,
                                                     _Float16* __restrict__ Vt) {
  __shared__ __align__(16) _Float16 Ts[64][72];
  const int t = threadIdx.x;
  const int n0 = blockIdx.x * 64;
  const int bh = blockIdx.y;
  const int b = bh >> 4, h = bh & 15;
  const _Float16* src = QKV + (size_t)(b * 2048 + n0) * 3072 + 2048 + h * 64;
#pragma unroll
  for (int i = 0; i < 2; i++) {
    const int s = i * 256 + t, r = s >> 3, c = (s & 7) * 8;
    *reinterpret_cast<hv8*>(&Ts[r][c]) = *reinterpret_cast<const hv8*>(src + (size_t)r * 3072 + c);
  }
  __syncthreads();
  _Float16* dst = Vt + (size_t)bh * 64 * 2048 + n0;
#pragma unroll
  for (int i = 0; i < 2; i++) {
    const int s = i * 256 + t, c = s >> 3, r0 = (s & 7) * 8;
    hv8 o;
#pragma unroll
    for (int k = 0; k < 8; k++) o[k] = Ts[r0 + k][c];
    *reinterpret_cast<hv8*>(dst + (size_t)c * 2048 + r0) = o;
  }
}

// ---------------- NT GEMM: C[m][n] = sum_k A[m][k] * B[n][k] ----------------
// BM x 128 tile, BK=32, 4 waves (2x2), each wave (BM/2) x 64.  (unchanged from R3)
template <int BM, typename OutT>
__global__ __launch_bounds__(256) void gemm_nt(const _Float16* __restrict__ A,
                                               const _Float16* __restrict__ B,
                                               OutT* __restrict__ C,
                                               const int M, const int N, const int K) {
  constexpr int MI = BM / 32;
  constexpr int ALOADS = BM / 64;
  __shared__ __align__(16) _Float16 As[BM * 32];
  __shared__ __align__(16) _Float16 Bs[128 * 32];
  const int t = threadIdx.x;
  const int w = t >> 6, lane = t & 63;
  const int wr = w >> 1, wc = w & 1;
  const int g = lane >> 4, lr = lane & 15;
  const int mBase = blockIdx.y * BM, nBase = blockIdx.x * 128;

  f32x4 acc[MI][4];
#pragma unroll
  for (int a = 0; a < MI; a++)
#pragma unroll
    for (int bb = 0; bb < 4; bb++) acc[a][bb] = {0.f, 0.f, 0.f, 0.f};

  const int srow = t >> 2;
  const int scol = (t & 3) * 8;
  for (int k0 = 0; k0 < K; k0 += 32) {
#pragma unroll
    for (int i = 0; i < ALOADS; i++) {
      const _Float16* ga = A + (size_t)(mBase + i * 64 + srow) * K + k0 + scol;
      __builtin_amdgcn_global_load_lds(GLB_AS(ga), LDS_AS(As + (i * 256 + w * 64) * 8), 16, 0, 0);
    }
#pragma unroll
    for (int i = 0; i < 2; i++) {
      const _Float16* gb = B + (size_t)(nBase + i * 64 + srow) * K + k0 + scol;
      __builtin_amdgcn_global_load_lds(GLB_AS(gb), LDS_AS(Bs + (i * 256 + w * 64) * 8), 16, 0, 0);
    }
    __syncthreads();
    hv8 af[MI], bfr[4];
#pragma unroll
    for (int mi = 0; mi < MI; mi++)
      af[mi] = *reinterpret_cast<const hv8*>(As + (wr * (BM / 2) + mi * 16 + lr) * 32 + g * 8);
#pragma unroll
    for (int ni = 0; ni < 4; ni++)
      bfr[ni] = *reinterpret_cast<const hv8*>(Bs + (wc * 64 + ni * 16 + lr) * 32 + g * 8);
#pragma unroll
    for (int mi = 0; mi < MI; mi++)
#pragma unroll
      for (int ni = 0; ni < 4; ni++)
        acc[mi][ni] = __builtin_amdgcn_mfma_f32_16x16x32_f16(af[mi], bfr[ni], acc[mi][ni], 0, 0, 0);
    __syncthreads();
  }
#pragma unroll
  for (int mi = 0; mi < MI; mi++) {
#pragma unroll
    for (int j = 0; j < 4; j++) {
      const size_t row = mBase + wr * (BM / 2) + mi * 16 + g * 4 + j;
#pragma unroll
      for (int ni = 0; ni < 4; ni++) {
        const int col = nBase + wc * 64 + ni * 16 + lr;
        C[row * N + col] = (OutT)acc[mi][ni][j];
      }
    }
  }
}

// ---------------- flash causal attention, swapped-operand / in-register softmax ----------------
// 4 waves/block; block = 64 q-rows of one (b,h); wave w owns 16 q-rows.
// Swapped QK^T: S^T = mfma(K,Q) so each lane's 16 S-values all belong to q = qw + (lane&15).
// PV computed as O^T = mfma(V^T, P^T) with kv-slot permutation pi(g*8+i) = (i>>2)*16+g*4+(i&3)
// applied to BOTH operands -> P fragment is lane-local (zero shuffles), V^T frag = 2x ds_read_b64.
// Online-softmax state (m,l) is a per-lane scalar; O^T rescale is lane-uniform.
__global__ __launch_bounds__(256) void attn_kernel(const _Float16* __restrict__ QKV,
                                                   const _Float16* __restrict__ Vt,
                                                   _Float16* __restrict__ O) {
  __shared__ __align__(16) _Float16 Ks[64 * 64];
  __shared__ __align__(16) _Float16 Vs[64 * 64];
  const int t = threadIdx.x;
  const int w = t >> 6, lane = t & 63;
  const int g = lane >> 4, lr = lane & 15;
  const int m0 = (int)(gridDim.x - 1 - blockIdx.x) * 64;  // heavy-first dispatch
  const int bh = blockIdx.y;
  const int b = bh >> 4, h = bh & 15;
  const _Float16* Qp = QKV + (size_t)b * 2048 * 3072 + h * 64;
  const _Float16* Kp = Qp + 1024;
  const _Float16* Vp = Vt + (size_t)bh * 64 * 2048;
  _Float16* Op = O + (size_t)b * 2048 * 1024 + h * 64;

  const int qg = m0 + w * 16 + lr;  // this lane's q row (all its S/O values belong to it)

  // Q B-frag (n=q=lr, k=g*8+i), pre-scaled by 1/sqrt(64) (exact pow2)
  hv8 qf[2];
#pragma unroll
  for (int ks = 0; ks < 2; ks++) {
    qf[ks] = *reinterpret_cast<const hv8*>(Qp + (size_t)qg * 3072 + ks * 32 + g * 8);
    qf[ks] = qf[ks] * (_Float16)0.125f;
  }

  f32x4 oacc[4];  // O^T frags: row = d(dblk*16+g*4+j), col = q (lane-local)
#pragma unroll
  for (int d = 0; d < 4; d++) oacc[d] = {0.f, 0.f, 0.f, 0.f};
  float mst = -INFINITY, lst = 0.f;

  for (int kv0 = 0; kv0 <= m0; kv0 += 64) {
    // stage K tile [64 kv][64 d] and V tile [64 d][64 kv], XOR-swizzled source
#pragma unroll
    for (int i = 0; i < 2; i++) {
      const int s = i * 256 + t;
      const int r = s >> 3;
      const int cs = ((s & 7) ^ (r & 7)) * 8;
      __builtin_amdgcn_global_load_lds(GLB_AS(Kp + (size_t)(kv0 + r) * 3072 + cs),
                                       LDS_AS(Ks + (i * 256 + w * 64) * 8), 16, 0, 0);
      __builtin_amdgcn_global_load_lds(GLB_AS(Vp + (size_t)r * 2048 + kv0 + cs),
                                       LDS_AS(Vs + (i * 256 + w * 64) * 8), 16, 0, 0);
    }
    __syncthreads();

    // S^T = K Q^T : A = K rows (m=kv), B = Q (n=q). 4 kv-frags x 2 k-steps.
    f32x4 sf[4];
#pragma unroll
    for (int nf = 0; nf < 4; nf++) sf[nf] = {0.f, 0.f, 0.f, 0.f};
#pragma unroll
    for (int ks = 0; ks < 2; ks++)
#pragma unroll
      for (int nf = 0; nf < 4; nf++) {
        const hv8 kf = *reinterpret_cast<const hv8*>(
            Ks + (nf * 16 + lr) * 64 + (((ks * 4 + g) ^ (lr & 7)) * 8));
        sf[nf] = __builtin_amdgcn_mfma_f32_16x16x32_f16(kf, qf[ks], sf[nf], 0, 0, 0);
      }

    // lane (g,lr): sf[nf][j] = S[q = qg][kv = kv0 + nf*16 + g*4 + j]
    const bool diag = (kv0 == m0);
    float v[4][4];
#pragma unroll
    for (int nf = 0; nf < 4; nf++)
#pragma unroll
      for (int j = 0; j < 4; j++) {
        float x = sf[nf][j];
        if (diag && (kv0 + nf * 16 + g * 4 + j > qg)) x = -INFINITY;
        v[nf][j] = x;
      }

    // online softmax: in-lane reduce over 16, cross-g via 2 shfls
    float rm = v[0][0];
#pragma unroll
    for (int nf = 0; nf < 4; nf++)
#pragma unroll
      for (int j = 0; j < 4; j++) rm = fmaxf(rm, v[nf][j]);
    rm = fmaxf(rm, __shfl_xor(rm, 16));
    rm = fmaxf(rm, __shfl_xor(rm, 32));
    const float mn = fmaxf(mst, rm);
    const float corr = __expf(mst - mn);  // first tile: exp(-inf)=0
    float p[4][4];
    float rs = 0.f;
#pragma unroll
    for (int nf = 0; nf < 4; nf++)
#pragma unroll
      for (int j = 0; j < 4; j++) {
        p[nf][j] = __expf(v[nf][j] - mn);
        rs += p[nf][j];
      }
    rs += __shfl_xor(rs, 16);
    rs += __shfl_xor(rs, 32);
    lst = lst * corr + rs;
    mst = mn;
#pragma unroll
    for (int d = 0; d < 4; d++) oacc[d] *= corr;  // all 16 O values belong to qg

    // P^T B-frags, lane-local via pi-permutation: pf[ks][i] = P[qg][kv0+ks*32+pi(g*8+i)]
    hv8 pf[2];
#pragma unroll
    for (int ks = 0; ks < 2; ks++)
#pragma unroll
      for (int i = 0; i < 8; i++) pf[ks][i] = (_Float16)p[ks * 2 + (i >> 2)][i & 3];

    // O^T += V^T P^T : A = V^T rows (m=d), same pi on the k-slots -> two b64 reads
#pragma unroll
    for (int dblk = 0; dblk < 4; dblk++) {
      const int row = dblk * 16 + lr;
#pragma unroll
      for (int ks = 0; ks < 2; ks++) {
        const int col1 = ks * 32 + g * 4;        // pi slots i=0..3
        const int col2 = col1 + 16;              // pi slots i=4..7
        const hv4 a = *reinterpret_cast<const hv4*>(
            Vs + row * 64 + (((col1 >> 3) ^ (row & 7)) << 3) + (col1 & 7));
        const hv4 bb = *reinterpret_cast<const hv4*>(
            Vs + row * 64 + (((col2 >> 3) ^ (row & 7)) << 3) + (col2 & 7));
        hv8 vtf;
#pragma unroll
        for (int i = 0; i < 4; i++) { vtf[i] = a[i]; vtf[i + 4] = bb[i]; }
        oacc[dblk] = __builtin_amdgcn_mfma_f32_16x16x32_f16(vtf, pf[ks], oacc[dblk], 0, 0, 0);
      }
    }
    __syncthreads();  // protect Ks/Vs for next tile's staging
  }

  // epilogue: oacc[dblk][j] = O^T[d = dblk*16+g*4+j][qg] -> 4x 8B stores per lane
  const float inv = 1.0f / lst;
#pragma unroll
  for (int dblk = 0; dblk < 4; dblk++) {
    hv4 o;
#pragma unroll
    for (int j = 0; j < 4; j++) o[j] = (_Float16)(oacc[dblk][j] * inv);
    *reinterpret_cast<hv4*>(Op + (size_t)qg * 1024 + dblk * 16 + g * 4) = o;
  }
}

extern "C" void kernel_launch(void* const* d_in, const int* in_sizes, int n_in,
                              void* d_out, int out_size, void* d_ws, size_t ws_size,
                              hipStream_t stream) {
  const float* x = (const float*)d_in[0];
  const float* wq = (const float*)d_in[1];
  const float* wk = (const float*)d_in[2];
  const float* wv = (const float*)d_in[3];
  const float* wo = (const float*)d_in[4];
  float* out = (float*)d_out;
  char* ws = (char*)d_ws;
  const size_t MB = 1ull << 20;
  _Float16* xb   = (_Float16*)(ws + 0 * MB);   // 8 MB (A operand for QKV gemm)
  _Float16* wqkv = (_Float16*)(ws + 8 * MB);   // 6 MB (wq|wk|wv contiguous rows)
  _Float16* wob  = (_Float16*)(ws + 14 * MB);  // 2 MB
  _Float16* QKV  = (_Float16*)(ws + 16 * MB);  // 24 MB [4096][3072]
  _Float16* Vtb  = (_Float16*)(ws + 40 * MB);  // 8 MB  [32*64][2048]
  _Float16* Ab   = (_Float16*)(ws + 0 * MB);   // 8 MB  (reuses xb after QKV gemm)

  cvt_kernel<<<2048, 256, 0, stream>>>(x, xb, 4194304);
  cvt_w_kernel<<<4096, 256, 0, stream>>>(wq, wk, wv, wo, wqkv, wob);

  // fused Q|K|V projection: [4096][3072]
  gemm_nt<128, _Float16><<<dim3(24, 32), 256, 0, stream>>>(xb, wqkv, QKV, 4096, 3072, 1024);

  rope_kernel<<<16384, 256, 0, stream>>>(QKV);
  vtrans_kernel<<<dim3(32, 32), 256, 0, stream>>>(QKV, Vtb);

  attn_kernel<<<dim3(32, 32), 256, 0, stream>>>(QKV, Vtb, Ab);

  gemm_nt<64, float><<<dim3(8, 64), 256, 0, stream>>>(Ab, wob, out, 4096, 1024, 1024);
}